// Round 3
// baseline (1105.798 us; speedup 1.0000x reference)
//
#include <hip/hip_runtime.h>
#include <hip/hip_bf16.h>
#include <limits.h>

// TemporalEMA: out = ALPHA * warp(prev, mv) + (1-ALPHA) * cur
// R3: dynamic-bbox LDS staging of the gather footprint (kills TA cache-line
//     split serialization of y-divergent gathers), per-channel stage->compute,
//     fallback to direct global gather if bbox exceeds LDS cap (mv unbounded).

#define ALPHA 0.85f

constexpr int Bc = 4;
constexpr int Cc = 16;
constexpr int Hc = 1080;
constexpr int Wc = 1920;

constexpr int TW = 64;              // tile width  (lanes)
constexpr int TH = 36;              // tile height (1080 = 30*36)
constexpr int PPT = TW * TH / 256;  // 9 pixels per thread
constexpr int NX = Wc / TW;         // 30
constexpr int NY = Hc / TH;         // 30
constexpr int NBLK = Bc * NY * NX;  // 3600
constexpr int NXCD = 8;
constexpr int CHUNK = NBLK / NXCD;  // 450 (divisible -> bijective swizzle)
constexpr int LDS_CAP = 12288;      // floats (48 KB) -> 3 blocks/CU

__global__ __launch_bounds__(256) void TemporalEMA_73194832658797_kernel(
    const float* __restrict__ cur,
    const float* __restrict__ prev,
    const float* __restrict__ mv,
    float* __restrict__ out)
{
    __shared__ float tile[LDS_CAP];
    __shared__ int sbox[4];  // ymin, ymax, xmin, xmax

    // chunked XCD swizzle: contiguous work slab per XCD -> halo reuse in its L2
    const int bid  = blockIdx.x;
    const int work = (bid % NXCD) * CHUNK + bid / NXCD;

    const int tx  = work % NX;
    const int rem = work / NX;
    const int ty  = rem % NY;
    const int b   = rem / NY;

    const int lw  = threadIdx.x & 63;
    const int lh0 = threadIdx.x >> 6;      // 0..3
    const int w     = tx * TW + lw;
    const int hbase = ty * TH + lh0;

    const size_t plane  = (size_t)Hc * Wc;
    const size_t base_b = (size_t)b * Cc * plane;
    const float sxk = (float)(Wc - 1) / (float)Wc;
    const float syk = (float)(Hc - 1) / (float)Hc;

    // ---- pass 1: per-pixel sample params + bbox ----
    int   x0v[PPT], y0v[PPT];
    float wxv[PPT], wyv[PPT];
    int ymn = INT_MAX, ymx = INT_MIN, xmn = INT_MAX, xmx = INT_MIN;

    #pragma unroll
    for (int i = 0; i < PPT; ++i) {
        const int h = hbase + 4 * i;                 // rows lh0+4i cover 0..35
        const size_t pix = (size_t)h * Wc + w;
        const float mvx = __builtin_nontemporal_load(&mv[((size_t)b * 2 + 0) * plane + pix]);
        const float mvy = __builtin_nontemporal_load(&mv[((size_t)b * 2 + 1) * plane + pix]);
        float px = fminf(fmaxf((float)w - mvx * sxk, 0.0f), (float)(Wc - 1));
        float py = fminf(fmaxf((float)h - mvy * syk, 0.0f), (float)(Hc - 1));
        const float x0f = floorf(px);
        const float y0f = floorf(py);
        x0v[i] = (int)x0f;  y0v[i] = (int)y0f;
        wxv[i] = px - x0f;  wyv[i] = py - y0f;
        ymn = min(ymn, y0v[i]); ymx = max(ymx, y0v[i]);
        xmn = min(xmn, x0v[i]); xmx = max(xmx, x0v[i]);
    }

    // block bbox: wave butterfly reduce, then one shared atomic per wave
    if (threadIdx.x < 4) { sbox[0] = INT_MAX; sbox[1] = INT_MIN; sbox[2] = INT_MAX; sbox[3] = INT_MIN; }
    __syncthreads();
    #pragma unroll
    for (int off = 32; off; off >>= 1) {
        ymn = min(ymn, __shfl_xor(ymn, off));
        ymx = max(ymx, __shfl_xor(ymx, off));
        xmn = min(xmn, __shfl_xor(xmn, off));
        xmx = max(xmx, __shfl_xor(xmx, off));
    }
    if ((threadIdx.x & 63) == 0) {
        atomicMin(&sbox[0], ymn); atomicMax(&sbox[1], ymx);
        atomicMin(&sbox[2], xmn); atomicMax(&sbox[3], xmx);
    }
    __syncthreads();
    const int bymin = sbox[0];
    const int bxmin = sbox[2];
    const int yend  = min(sbox[1] + 1, Hc - 1);
    const int xend  = min(sbox[3] + 1, Wc - 1);
    const int RH = yend - bymin + 1;
    const int RW = xend - bxmin + 1;
    const int stride = RW | 1;                  // odd stride: spread LDS banks

    if (RH * stride <= LDS_CAP) {
        // ---- staged path ----
        int off00[PPT], dxo[PPT], dyo[PPT];
        #pragma unroll
        for (int i = 0; i < PPT; ++i) {
            off00[i] = (y0v[i] - bymin) * stride + (x0v[i] - bxmin);
            dxo[i]   = (x0v[i] < Wc - 1) ? 1 : 0;
            dyo[i]   = (y0v[i] < Hc - 1) ? stride : 0;
        }

        for (int c = 0; c < Cc; ++c) {
            __syncthreads();   // previous channel's compute done before overwrite
            const float* __restrict__ src = prev + base_b + (size_t)c * plane;
            for (int r = lh0; r < RH; r += 4) {
                const size_t rowbase = (size_t)(bymin + r) * Wc + bxmin;
                for (int ci = lw; ci < RW; ci += 64)
                    tile[r * stride + ci] = src[rowbase + ci];
            }
            __syncthreads();

            const size_t cb = base_b + (size_t)c * plane;
            #pragma unroll
            for (int i = 0; i < PPT; ++i) {
                const int o = off00[i];
                const float v00 = tile[o];
                const float v01 = tile[o + dxo[i]];
                const float v10 = tile[o + dyo[i]];
                const float v11 = tile[o + dyo[i] + dxo[i]];
                const float wx = wxv[i], wy = wyv[i];
                const float warped = (v00 * (1.0f - wx) + v01 * wx) * (1.0f - wy)
                                   + (v10 * (1.0f - wx) + v11 * wx) * wy;
                const size_t pix = (size_t)(hbase + 4 * i) * Wc + w;
                const float cu = __builtin_nontemporal_load(&cur[cb + pix]);
                __builtin_nontemporal_store(ALPHA * warped + (1.0f - ALPHA) * cu,
                                            &out[cb + pix]);
            }
        }
    } else {
        // ---- fallback: direct global gather (bbox too large; ~never taken) ----
        #pragma unroll
        for (int i = 0; i < PPT; ++i) {
            const int x0 = x0v[i], y0 = y0v[i];
            const int x1 = min(x0 + 1, Wc - 1);
            const int y1 = min(y0 + 1, Hc - 1);
            const float wx = wxv[i], wy = wyv[i];
            const size_t o00 = (size_t)y0 * Wc + x0;
            const size_t o01 = (size_t)y0 * Wc + x1;
            const size_t o10 = (size_t)y1 * Wc + x0;
            const size_t o11 = (size_t)y1 * Wc + x1;
            const size_t pix = (size_t)(hbase + 4 * i) * Wc + w;
            for (int c = 0; c < Cc; ++c) {
                const size_t cb = base_b + (size_t)c * plane;
                const float v00 = prev[cb + o00];
                const float v01 = prev[cb + o01];
                const float v10 = prev[cb + o10];
                const float v11 = prev[cb + o11];
                const float warped = (v00 * (1.0f - wx) + v01 * wx) * (1.0f - wy)
                                   + (v10 * (1.0f - wx) + v11 * wx) * wy;
                const float cu = __builtin_nontemporal_load(&cur[cb + pix]);
                __builtin_nontemporal_store(ALPHA * warped + (1.0f - ALPHA) * cu,
                                            &out[cb + pix]);
            }
        }
    }
}

extern "C" void kernel_launch(void* const* d_in, const int* in_sizes, int n_in,
                              void* d_out, int out_size, void* d_ws, size_t ws_size,
                              hipStream_t stream) {
    const float* cur  = (const float*)d_in[0];
    const float* prev = (const float*)d_in[1];
    const float* mv   = (const float*)d_in[2];
    float* out = (float*)d_out;

    TemporalEMA_73194832658797_kernel<<<NBLK, 256, 0, stream>>>(cur, prev, mv, out);
}

// Round 4
// 666.081 us; speedup vs baseline: 1.6602x; 1.6602x over previous
//
#include <hip/hip_runtime.h>
#include <hip/hip_bf16.h>

// TemporalEMA: out = ALPHA * bilinear_warp(prev, mv) + (1-ALPHA) * cur
// R4: back to direct-gather R2 structure (LDS staging regressed: occupancy 33%,
//     3.9e7 bank conflicts). Fuse x-adjacent taps into ONE dwordx2 pair load
//     (v00,v01) and (v10,v11): halves TA line-lookup serialization, which is
//     the measured wall (BW 1.6 TB/s @ VALU 9% = address-unit bound).
//     Border clamp folded into weights: x0=min(x0,W-2), wx=px-x0 (wx->1 at
//     right border reproduces clamp exactly); same for y.

#define ALPHA 0.85f

constexpr int Bc = 4;
constexpr int Cc = 16;
constexpr int Hc = 1080;
constexpr int Wc = 1920;

constexpr int TW = 64;             // tile width (one wave row)
constexpr int TH = 4;              // tile height (4 waves/block)
constexpr int NX = Wc / TW;        // 30
constexpr int NY = Hc / TH;        // 270
constexpr int NBLK = Bc * NY * NX; // 32400
constexpr int NXCD = 8;
constexpr int CHUNK = NBLK / NXCD; // 4050 (divisible -> bijective swizzle)

typedef float f2 __attribute__((ext_vector_type(2)));

__global__ __launch_bounds__(256) void TemporalEMA_73194832658797_kernel(
    const float* __restrict__ cur,
    const float* __restrict__ prev,
    const float* __restrict__ mv,
    float* __restrict__ out)
{
    // chunked XCD swizzle: contiguous slab per XCD -> y-halo reuse in its L2
    const int bid  = blockIdx.x;
    const int work = (bid % NXCD) * CHUNK + bid / NXCD;

    const int tx  = work % NX;
    const int rem = work / NX;
    const int ty  = rem % NY;
    const int b   = rem / NY;

    const int lane_w = threadIdx.x & (TW - 1);
    const int lane_h = threadIdx.x / TW;
    const int w = tx * TW + lane_w;
    const int h = ty * TH + lane_h;

    const size_t plane = (size_t)Hc * Wc;
    const size_t pix   = (size_t)h * Wc + w;

    const float mvx = __builtin_nontemporal_load(&mv[((size_t)b * 2 + 0) * plane + pix]);
    const float mvy = __builtin_nontemporal_load(&mv[((size_t)b * 2 + 1) * plane + pix]);

    const float sxk = (float)(Wc - 1) / (float)Wc;
    const float syk = (float)(Hc - 1) / (float)Hc;
    float px = fminf(fmaxf((float)w - mvx * sxk, 0.0f), (float)(Wc - 1));
    float py = fminf(fmaxf((float)h - mvy * syk, 0.0f), (float)(Hc - 1));

    // clamp base to interior; weights absorb the border shift exactly
    const int x0 = min((int)floorf(px), Wc - 2);
    const int y0 = min((int)floorf(py), Hc - 2);
    const float wx = px - (float)x0;   // in [0,1]; ==1 exactly at right border
    const float wy = py - (float)y0;

    const float w00 = (1.0f - wx) * (1.0f - wy);
    const float w01 = wx * (1.0f - wy);
    const float w10 = (1.0f - wx) * wy;
    const float w11 = wx * wy;

    const size_t o0 = (size_t)y0 * Wc + x0;        // pair (v00,v01)
    const size_t o1 = o0 + Wc;                     // pair (v10,v11)
    const size_t base_b = (size_t)b * Cc * plane;

    #pragma unroll
    for (int cg = 0; cg < Cc; cg += 4) {
        f2 p0[4], p1[4];
        float cu[4];
        #pragma unroll
        for (int j = 0; j < 4; ++j) {
            const size_t cb = base_b + (size_t)(cg + j) * plane;
            p0[j] = *(const f2*)(prev + cb + o0);
            p1[j] = *(const f2*)(prev + cb + o1);
            cu[j] = __builtin_nontemporal_load(&cur[cb + pix]);
        }
        #pragma unroll
        for (int j = 0; j < 4; ++j) {
            const size_t cb = base_b + (size_t)(cg + j) * plane;
            const float warped = p0[j].x * w00 + p0[j].y * w01
                               + p1[j].x * w10 + p1[j].y * w11;
            __builtin_nontemporal_store(ALPHA * warped + (1.0f - ALPHA) * cu[j],
                                        &out[cb + pix]);
        }
    }
}

extern "C" void kernel_launch(void* const* d_in, const int* in_sizes, int n_in,
                              void* d_out, int out_size, void* d_ws, size_t ws_size,
                              hipStream_t stream) {
    const float* cur  = (const float*)d_in[0];
    const float* prev = (const float*)d_in[1];
    const float* mv   = (const float*)d_in[2];
    float* out = (float*)d_out;

    TemporalEMA_73194832658797_kernel<<<NBLK, 256, 0, stream>>>(cur, prev, mv, out);
}